// Round 9
// baseline (214.465 us; speedup 1.0000x reference)
//
#include <hip/hip_runtime.h>
#include <hip/hip_bf16.h>
#include <cstdint>

namespace {
constexpr int H_  = 1536;
constexpr int NH_ = 24;
constexpr int HD_ = 64;
constexpr int B_  = 2;
constexpr int S_  = 2048;
constexpr int M_  = B_ * S_;          // 4096
constexpr int KD_ = H_;               // GEMM depth
}

typedef __attribute__((ext_vector_type(8)))  short bf16x8;
typedef __attribute__((ext_vector_type(4)))  float f32x4;
typedef __attribute__((ext_vector_type(16))) float f32x16;

// fp32 -> bf16, round-half-up (2 VALU ops; vs ~5 for RNE emulation)
__device__ __forceinline__ unsigned short f2bf_fast(float x) {
    return (unsigned short)((__float_as_uint(x) + 0x8000u) >> 16);
}
// two fp32 -> packed bf16x2 in a u32 (lo = a, hi = b), round-half-up
__device__ __forceinline__ unsigned pack2bf(float b_hi, float a_lo) {
    const unsigned ub = __float_as_uint(b_hi) + 0x8000u;
    const unsigned ua = __float_as_uint(a_lo) + 0x8000u;
    return (ub & 0xffff0000u) | (ua >> 16);
}

__device__ __forceinline__ void gload16(const short* g, short* l) {
    __builtin_amdgcn_global_load_lds(
        (const __attribute__((address_space(1))) unsigned int*)g,
        (__attribute__((address_space(3))) unsigned int*)l, 16, 0, 0);
}

// ---------------------------------------------------------------------------
// Fused fp32 -> bf16 cast for X and the 4 weight matrices (one launch).
// ---------------------------------------------------------------------------
__global__ __launch_bounds__(256)
void cast_all(const float* __restrict__ X,
              const float* __restrict__ wq, const float* __restrict__ wk,
              const float* __restrict__ wv, const float* __restrict__ wo,
              short* __restrict__ Xh,
              short* __restrict__ Wqh, short* __restrict__ Wkh,
              short* __restrict__ Wvh, short* __restrict__ Woh)
{
    constexpr int XB = (M_*H_) / 1024;   // 6144 blocks for X
    constexpr int WB = (H_*H_) / 1024;   // 2304 blocks per weight
    const int bid = blockIdx.x;
    const float* src; short* dst; int off;
    if (bid < XB)            { src = X;  dst = Xh;  off = bid; }
    else {
        const int r = bid - XB, wsel = r / WB; off = r % WB;
        if      (wsel == 0)  { src = wq; dst = Wqh; }
        else if (wsel == 1)  { src = wk; dst = Wkh; }
        else if (wsel == 2)  { src = wv; dst = Wvh; }
        else                 { src = wo; dst = Woh; }
    }
    const int i = (off * 256 + threadIdx.x) * 4;
    const float4 v = *(const float4*)&src[i];
    uint2 o;
    o.x = pack2bf(v.y, v.x);
    o.y = pack2bf(v.w, v.z);
    *(uint2*)&dst[i] = o;
}

// ---------------------------------------------------------------------------
// bf16 GEMM (single pass):  C[M,N] = A[M,K] @ W[N,K]^T + bias, fp32 accum.
// m97-style structure: tile 128x128, BK=64, single-buffered LDS (32 KB),
// 2 barriers per K-step, global_load_lds w16 with inverse XOR swizzle on the
// GLOBAL source (rule 21); LDS frag reads conflict-free (measured 0).
// KIND 0 (QKV fused, grid 1152): z=0 Q (rope, scale=0.125*log2e), z=1 K
// (rope), z=2 V (bf16 transposed (b,h,d,s)).  KIND 1 (O-proj): fp32 + bias.
// Bijective XCD swizzle: m-tile from bid&7 -> A-tile stays in one XCD's L2.
// ---------------------------------------------------------------------------
template<int KIND>
__global__ __launch_bounds__(256, 4)
void gemm_bf16(const short* __restrict__ A_g,
               const short* __restrict__ Wq, const short* __restrict__ Wk,
               const short* __restrict__ Wv,
               const float* __restrict__ bq, const float* __restrict__ bk,
               const float* __restrict__ bv,
               const float* __restrict__ cosb, const float* __restrict__ sinb,
               short* __restrict__ Qb, short* __restrict__ Kb,
               short* __restrict__ Vt, float* __restrict__ outf)
{
    __shared__ short Ah[128*64], Bh[128*64];   // 16 KB each

    const int t    = threadIdx.x;
    const int lane = t & 63;
    const int w    = t >> 6;
    const int wr   = w >> 1, wc = w & 1;
    const int l15  = lane & 15;
    const int grp  = lane >> 4;

    // bijective XCD-aware decode: m fast (4 per XCD), then n, then z
    const int xcd = blockIdx.x & 7;
    const int off = blockIdx.x >> 3;
    const int m_idx = xcd * 4 + (off & 3);
    const int rest  = off >> 2;                  // QKV: 0..35, O: 0..11
    const int n_idx = rest % 12;
    const int zi    = (KIND == 0) ? rest / 12 : 3;

    const int m0 = m_idx * 128;
    const int n0 = n_idx * 128;

    const short* bhg; const float* bias;
    if (KIND == 0) {
        if      (zi == 0) { bhg = Wq; bias = bq; }
        else if (zi == 1) { bhg = Wk; bias = bk; }
        else              { bhg = Wv; bias = bv; }
    } else {
        bhg = Wq; bias = bq;                     // O-proj passes wo/bo here
    }

    f32x4 acc[4][4];
#pragma unroll
    for (int i = 0; i < 4; ++i)
#pragma unroll
        for (int j = 0; j < 4; ++j) acc[i][j] = (f32x4){0.f, 0.f, 0.f, 0.f};

    const int srow  = lane >> 3;
    const int sslot = (lane & 7) ^ srow;

    for (int kt = 0; kt < KD_; kt += 64) {
        __syncthreads();
#pragma unroll
        for (int cc = 0; cc < 4; ++cc) {
            const int c = w * 4 + cc;
            const int r = c * 8 + srow;
            gload16(A_g + (size_t)(m0 + r) * KD_ + kt + sslot * 8, Ah + c * 512);
            gload16(bhg + (size_t)(n0 + r) * KD_ + kt + sslot * 8, Bh + c * 512);
        }
        __syncthreads();

#pragma unroll
        for (int kk = 0; kk < 2; ++kk) {
            bf16x8 af[4], bfr[4];
#pragma unroll
            for (int i = 0; i < 4; ++i) {
                const int ra = wr * 64 + i * 16 + l15;
                af[i]  = *(const bf16x8*)&Ah[ra * 64 + (((kk*4 + grp) ^ (ra & 7)) << 3)];
                const int rb = wc * 64 + i * 16 + l15;
                bfr[i] = *(const bf16x8*)&Bh[rb * 64 + (((kk*4 + grp) ^ (rb & 7)) << 3)];
            }
#pragma unroll
            for (int i = 0; i < 4; ++i)
#pragma unroll
                for (int j = 0; j < 4; ++j)
                    acc[i][j] = __builtin_amdgcn_mfma_f32_16x16x32_bf16(af[i], bfr[j], acc[i][j], 0, 0, 0);
        }
    }

    // ---------------- epilogue ----------------
    float bn[4];
#pragma unroll
    for (int ni = 0; ni < 4; ++ni) bn[ni] = bias[n0 + wc * 64 + ni * 16 + l15];
    const int hw = (n0 + wc * 64) >> 6;          // head (tile 64-aligned)

    if (KIND == 1) {
#pragma unroll
        for (int mi = 0; mi < 4; ++mi)
#pragma unroll
            for (int r = 0; r < 4; ++r) {
                const int m = m0 + wr * 64 + mi * 16 + grp * 4 + r;
#pragma unroll
                for (int ni = 0; ni < 4; ++ni)
                    outf[(size_t)m * H_ + n0 + wc * 64 + ni * 16 + l15] =
                        acc[mi][ni][r] + bn[ni];
            }
        return;
    }

    if (zi == 2) {
        // V: bf16 transposed (b, h, d, s)
        const int b = m0 >> 11;
#pragma unroll
        for (int mi = 0; mi < 4; ++mi) {
            const int sb = (m0 & (S_ - 1)) + wr * 64 + mi * 16 + grp * 4;
#pragma unroll
            for (int ni = 0; ni < 4; ++ni) {
                const int d = ni * 16 + l15;
                uint2 o;
                o.x = pack2bf(acc[mi][ni][1] + bn[ni], acc[mi][ni][0] + bn[ni]);
                o.y = pack2bf(acc[mi][ni][3] + bn[ni], acc[mi][ni][2] + bn[ni]);
                *(uint2*)&Vt[((size_t)(b * NH_ + hw) * HD_ + d) * S_ + sb] = o;
            }
        }
        return;
    }

    // Q/K: rope + scale + bf16 head-major (b,h,s,d); partner d^32 = acc[..][ni^2]
    // Q carries 0.125*log2(e) so attention scores are already in exp2 domain.
    const float sc = (zi == 0) ? 0.18033688011112042f : 1.0f;
    short* dst = (zi == 0) ? Qb : Kb;
#pragma unroll
    for (int mi = 0; mi < 4; ++mi)
#pragma unroll
        for (int r = 0; r < 4; ++r) {
            const int m = m0 + wr * 64 + mi * 16 + grp * 4 + r;
            const int b = m >> 11;
            const int s = m & (S_ - 1);
#pragma unroll
            for (int ni = 0; ni < 4; ++ni) {
                const int d  = ni * 16 + l15;
                const float val = acc[mi][ni][r] + bn[ni];
                const float pv  = acc[mi][ni ^ 2][r] + bn[ni ^ 2];
                const float cs = cosb[s * HD_ + d];
                const float sn = sinb[s * HD_ + d];
                const float rot = (ni < 2) ? -pv : pv;
                dst[((size_t)(b * NH_ + hw) * S_ + s) * HD_ + d] =
                    (short)f2bf_fast((val * cs + rot * sn) * sc);
            }
        }
}

// ---------------------------------------------------------------------------
// Flash attention, bf16 MFMA **32x32x16**, fp32 accum, non-causal.
// Rationale (R8 post-mortem): attn was LDS-pipe-bound (~60us of LDS traffic).
// A 32x32x16 MFMA reads the same bytes/operand as 16x16x32 but does 2x the
// FLOPs -> frag reads per output halve.  Wave owns 32 q-rows (Q = 4 B-frags
// in regs), KV tile 64: QK = 8 MFMA, PV = 8 MFMA.  P via per-wave LDS
// [32 q][64 kv], 16B-slot ^(q&7) swizzle (write u32 2/bank-free, read b128
// 2-way-free).  C layout: col=lane&31 (=q), row=(r&3)+8*(r>>2)+4*(lane>>5).
// Fixed-max exp2 softmax, deferred denominator (one shfl_xor(32) at end).
// 4 waves x 32 q = 128 q/block; grid 768 = 3 blocks/CU (LDS 48 KB).
// ---------------------------------------------------------------------------
__global__ __launch_bounds__(256, 3)
void attn_mfma(const short* __restrict__ Q, const short* __restrict__ K,
               const short* __restrict__ Vt, short* __restrict__ AO)
{
    __shared__ short Ks[2][4096];    // [kv=64][d=64] swizzled, 8 KB per buf
    __shared__ short Vs[2][4096];    // [d=64][kv=64] swizzled, 8 KB per buf
    __shared__ short Ps[4][2048];    // per-wave [q=32][kv=64] swizzled, 4 KB/wave

    const int t    = threadIdx.x;
    const int lane = t & 63;
    const int wid  = t >> 6;         // 0..3
    const int bh   = blockIdx.y;
    const int q0   = blockIdx.x * 128;

    const int l31 = lane & 31;       // q column (C/B frag) or row (A frag)
    const int hi  = lane >> 5;       // k-half selector in A/B frags
    const int sw7 = lane & 7;        // swizzle key (row & 7)

    const short* Qg = Q  + ((size_t)bh * S_ + q0 + wid*32) * HD_;
    const short* Kg = K  + (size_t)bh * S_ * HD_;
    const short* Vg = Vt + (size_t)bh * HD_ * S_;

    // Q as B-operand fragments: lane holds Q[q=l31][d = kk*16 + hi*8 + j]
    bf16x8 qf[4];
#pragma unroll
    for (int kk = 0; kk < 4; ++kk)
        qf[kk] = *(const bf16x8*)(Qg + (size_t)l31*HD_ + kk*16 + hi*8);

    f32x16 oacc[2];                  // O^T[d = nt*32 + crow][q = l31]
#pragma unroll
    for (int nt = 0; nt < 2; ++nt)
#pragma unroll
        for (int r = 0; r < 16; ++r) oacc[nt][r] = 0.f;
    float lacc = 0.f;                // per-lane partial; reduced at end

    auto stageKV = [&](int b, int kt) {
#pragma unroll
        for (int cc = 0; cc < 2; ++cc) {
            const int d   = cc * 256 + t;        // 0..511
            const int row = d >> 3;              // 0..63
            const int sg  = (d & 7) ^ (row & 7); // inverse swizzle on source
            gload16(Kg + (size_t)(kt + row) * HD_ + sg * 8, &Ks[b][d * 8]);
            gload16(Vg + (size_t)row * S_ + kt + sg * 8,    &Vs[b][d * 8]);
        }
    };

    stageKV(0, 0);
    __syncthreads();
    int cur = 0;

    for (int kt = 0; kt < S_; kt += 64) {
        if (kt + 64 < S_) stageKV(cur ^ 1, kt + 64);

        // S^T = K * Q^T  (scores already in exp2 domain via Q scale)
        f32x16 sac[2];
#pragma unroll
        for (int nt = 0; nt < 2; ++nt)
#pragma unroll
            for (int r = 0; r < 16; ++r) sac[nt][r] = 0.f;
        __builtin_amdgcn_s_setprio(1);
#pragma unroll
        for (int kk = 0; kk < 4; ++kk) {
#pragma unroll
            for (int nt = 0; nt < 2; ++nt) {
                const int row = nt*32 + l31;
                const bf16x8 kfrag = *(const bf16x8*)
                    &Ks[cur][row*64 + (((kk*2 + hi) ^ sw7) << 3)];
                sac[nt] = __builtin_amdgcn_mfma_f32_32x32x16_bf16(kfrag, qf[kk], sac[nt], 0, 0, 0);
            }
        }
        __builtin_amdgcn_s_setprio(0);

        // fixed-max softmax: p = 2^s; denominator accumulated per-lane
#pragma unroll
        for (int nt = 0; nt < 2; ++nt)
#pragma unroll
            for (int r = 0; r < 16; ++r) {
                sac[nt][r] = exp2f(sac[nt][r]);
                lacc += sac[nt][r];
            }

        // P^T -> per-wave LDS as packed bf16x2.
        // reg r of sac[h]: kv = h*32 + (r&3) + 8*(r>>2) + 4*hi; pairs (2i,2i+1)
#pragma unroll
        for (int h = 0; h < 2; ++h)
#pragma unroll
            for (int i = 0; i < 8; ++i) {
                const int crow = ((2*i) & 3) + 8*((2*i) >> 2) + 4*hi;
                const int kv   = h*32 + crow;
                const int idx  = l31*64 + ((((kv >> 3) ^ sw7)) << 3) + (kv & 7);
                *(unsigned*)&Ps[wid][idx] = pack2bf(sac[h][2*i+1], sac[h][2*i]);
            }

        // O^T += V^T * P^T   (A = V^T rows d, B = P^T from per-wave LDS)
        __builtin_amdgcn_s_setprio(1);
#pragma unroll
        for (int ks = 0; ks < 4; ++ks) {
            const bf16x8 pfrag = *(const bf16x8*)
                &Ps[wid][l31*64 + (((ks*2 + hi) ^ sw7) << 3)];
#pragma unroll
            for (int nt = 0; nt < 2; ++nt) {
                const int row = nt*32 + l31;
                const bf16x8 vfrag = *(const bf16x8*)
                    &Vs[cur][row*64 + (((ks*2 + hi) ^ sw7) << 3)];
                oacc[nt] = __builtin_amdgcn_mfma_f32_32x32x16_bf16(vfrag, pfrag, oacc[nt], 0, 0, 0);
            }
        }
        __builtin_amdgcn_s_setprio(0);

        __syncthreads();
        cur ^= 1;
    }

    // final denominator reduction: lane l and l^32 hold complementary kv sets
    lacc += __shfl_xor(lacc, 32);
    const float inv = 1.f / lacc;

    const int b = bh / NH_, h = bh % NH_;
    const int srow = q0 + wid*32 + l31;
    const size_t rowb = ((size_t)(b*S_ + srow)) * H_ + h*HD_;
#pragma unroll
    for (int nt = 0; nt < 2; ++nt)
#pragma unroll
        for (int i = 0; i < 8; ++i) {
            const int crow = ((2*i) & 3) + 8*((2*i) >> 2) + 4*hi;
            const int d    = nt*32 + crow;
            *(unsigned*)&AO[rowb + d] =
                pack2bf(oacc[nt][2*i+1]*inv, oacc[nt][2*i]*inv);
        }
}

// ---------------------------------------------------------------------------
extern "C" void kernel_launch(void* const* d_in, const int* in_sizes, int n_in,
                              void* d_out, int out_size, void* d_ws, size_t ws_size,
                              hipStream_t stream)
{
    const float* X    = (const float*)d_in[0];
    const float* cosb = (const float*)d_in[1];
    const float* sinb = (const float*)d_in[2];
    const float* wq   = (const float*)d_in[3];
    const float* bq   = (const float*)d_in[4];
    const float* wk   = (const float*)d_in[5];
    const float* bk   = (const float*)d_in[6];
    const float* wv   = (const float*)d_in[7];
    const float* bv   = (const float*)d_in[8];
    const float* wo   = (const float*)d_in[9];
    const float* bo   = (const float*)d_in[10];
    float* out = (float*)d_out;

    const size_t MH = (size_t)M_ * H_;      // 6.29M
    const size_t HH = (size_t)H_ * H_;      // 2.36M

    short* Xh  = (short*)d_ws;
    short* Wqh = Xh  + MH;
    short* Wkh = Wqh + HH;
    short* Wvh = Wkh + HH;
    short* Woh = Wvh + HH;
    short* Qb  = Woh + HH;
    short* Kb  = Qb + MH;
    short* Vt  = Kb + MH;
    short* AO  = Vt + MH;

    cast_all<<<(int)(MH/1024 + 4*(HH/1024)), 256, 0, stream>>>(
        X, wq, wk, wv, wo, Xh, Wqh, Wkh, Wvh, Woh);

    gemm_bf16<0><<<1152, 256, 0, stream>>>(Xh, Wqh, Wkh, Wvh,
        bq, bk, bv, cosb, sinb, Qb, Kb, Vt, nullptr);

    attn_mfma<<<dim3(S_/128, B_*NH_), 256, 0, stream>>>(Qb, Kb, Vt, AO);

    gemm_bf16<1><<<384, 256, 0, stream>>>(AO, Woh, nullptr, nullptr,
        bo, nullptr, nullptr, nullptr, nullptr, nullptr, nullptr, nullptr, out);
}